// Round 5
// baseline (1610.180 us; speedup 1.0000x reference)
//
#include <hip/hip_runtime.h>
#include <hip/hip_bf16.h>

#define DIM 64
#define NCLS_OUT 40

typedef __hip_bfloat16 bf16;

__device__ __forceinline__ float lane_bcast(float v, int l) {
  return __int_as_float(__builtin_amdgcn_readlane(__float_as_int(v), l));
}
__device__ __forceinline__ unsigned short f2bf_bits(float f) {
  bf16 h = __float2bfloat16(f);
  return *reinterpret_cast<unsigned short*>(&h);
}

// mode: 1 = float inputs/outputs stored as f32, 0 = stored as bf16
__device__ __forceinline__ float ldf(const void* p, long i, int m) {
  return m ? ((const float*)p)[i] : __bfloat162float(((const bf16*)p)[i]);
}
__device__ __forceinline__ void stf(void* p, long i, float v, int m) {
  if (m) ((float*)p)[i] = v;
  else ((bf16*)p)[i] = __float2bfloat16(v);
}

// ---- dtype detector ----
__global__ void k_detect(const unsigned int* __restrict__ wds, int nw, int* __restrict__ mode) {
  __shared__ int cnt_s;
  if (threadIdx.x == 0) cnt_s = 0;
  __syncthreads();
  int c = 0;
  for (int i = threadIdx.x; i < nw; i += 1024) {
    unsigned h = wds[i] & 0xFFFFu;
    unsigned e = (h >> 7) & 0xFFu;
    if (e == 0xFFu || (e != 0u && e < 0x60u)) c++;
  }
  atomicAdd(&cnt_s, c);
  __syncthreads();
  if (threadIdx.x == 0) *mode = (cnt_s > nw / 16) ? 1 : 0;
}

// ---- degree count, both graphs, one dispatch ----
// deg layout: [d1in | d2in | d1out | d2out] (in-degrees first so scan input is contiguous)
__global__ void k_deg_all(const int* __restrict__ src1, const int* __restrict__ dst1,
                          const int* __restrict__ src2, const int* __restrict__ dst2,
                          int* __restrict__ deg, int n, int e1, int etot) {
  int i = blockIdx.x * 256 + threadIdx.x;
  if (i >= etot) return;
  if (i < e1) {
    atomicAdd(&deg[dst1[i]], 1);            // d1in
    atomicAdd(&deg[2 * n + src1[i]], 1);    // d1out
  } else {
    int j = i - e1;
    atomicAdd(&deg[n + dst2[j]], 1);        // d2in
    atomicAdd(&deg[3 * n + src2[j]], 1);    // d2out
  }
}

// ---- norms = rsqrt(max(deg,1)); layout mirrors deg: [nd1|nd2|ns1|ns2] ----
__global__ void k_norm(const int* __restrict__ deg, float* __restrict__ nrm, int n4) {
  int i = blockIdx.x * 256 + threadIdx.x;
  if (i < n4) {
    int d = deg[i];
    if (d < 1) d = 1;
    nrm[i] = rsqrtf((float)d);
  }
}

// ---- scan pass 1 ----
__global__ void k_scan1(const int* __restrict__ x, int* __restrict__ bsum, int n) {
  __shared__ int sm[256];
  int t = threadIdx.x;
  int base = blockIdx.x * 1024 + t * 4;
  int s = 0;
#pragma unroll
  for (int k = 0; k < 4; ++k) {
    int i = base + k;
    if (i < n) s += x[i];
  }
  sm[t] = s;
  __syncthreads();
  for (int o = 128; o > 0; o >>= 1) {
    if (t < o) sm[t] += sm[t + o];
    __syncthreads();
  }
  if (t == 0) bsum[blockIdx.x] = sm[0];
}

// ---- scan pass 2 ----
__global__ void k_scan2(int* __restrict__ bsum, int nb) {
  __shared__ int sm[256];
  __shared__ int carry_s;
  int t = threadIdx.x;
  if (t == 0) carry_s = 0;
  __syncthreads();
  for (int base = 0; base < nb; base += 256) {
    int i = base + t;
    int v = (i < nb) ? bsum[i] : 0;
    sm[t] = v;
    __syncthreads();
    for (int o = 1; o < 256; o <<= 1) {
      int a = (t >= o) ? sm[t - o] : 0;
      __syncthreads();
      sm[t] += a;
      __syncthreads();
    }
    int incl = sm[t];
    int tot = sm[255];
    int c = carry_s;
    __syncthreads();
    if (i < nb) bsum[i] = c + incl - v;
    if (t == 0) carry_s = c + tot;
    __syncthreads();
  }
}

// ---- scan pass 3 ----
__global__ void k_scan3(const int* __restrict__ x, const int* __restrict__ bsum,
                        int* __restrict__ rp, int n, int e) {
  __shared__ int sm[256];
  int t = threadIdx.x;
  int base = blockIdx.x * 1024;
  int v[4];
  int s = 0;
#pragma unroll
  for (int k = 0; k < 4; ++k) {
    int i = base + t * 4 + k;
    v[k] = (i < n) ? x[i] : 0;
    s += v[k];
  }
  sm[t] = s;
  __syncthreads();
  for (int o = 1; o < 256; o <<= 1) {
    int a = (t >= o) ? sm[t - o] : 0;
    __syncthreads();
    sm[t] += a;
    __syncthreads();
  }
  int excl = bsum[blockIdx.x] + sm[t] - s;
#pragma unroll
  for (int k = 0; k < 4; ++k) {
    int i = base + t * 4 + k;
    if (i < n) {
      rp[i] = excl;
      excl += v[k];
    }
  }
  if (blockIdx.x == 0 && t == 0) rp[n] = e;
}

// ---- bucket fill, both graphs, unified sb ----
__global__ void k_fill_all(const int* __restrict__ src1, const int* __restrict__ dst1,
                           const int* __restrict__ src2, const int* __restrict__ dst2,
                           int* __restrict__ cur, int* __restrict__ sb,
                           int n, int e1, int etot) {
  int i = blockIdx.x * 256 + threadIdx.x;
  if (i >= etot) return;
  int s, ridx;
  if (i < e1) { s = src1[i]; ridx = dst1[i]; }
  else { int j = i - e1; s = src2[j]; ridx = n + dst2[j]; }
  int pos = atomicAdd(&cur[ridx], 1);
  if ((unsigned)pos < (unsigned)etot) sb[pos] = s;
}

// ---- P = feat * ns, both graphs -> interleaved P[2n][64] ----
__global__ void k_scale_all(const void* __restrict__ f1, const void* __restrict__ f2,
                            const float* __restrict__ norms, bf16* __restrict__ P,
                            int n, const int* __restrict__ mode) {
  int m = *mode;
  int i = blockIdx.x * 256 + threadIdx.x;
  int nd = n * DIM;
  if (i >= 2 * nd) return;
  int g = i >= nd;
  int li = g ? i - nd : i;
  float ns = norms[2 * n + g * n + (li >> 6)];  // ns1/ns2
  P[i] = __float2bfloat16(ldf(g ? f2 : f1, li, m) * ns);
}

// ---- P = feat * ns, one graph (sequential fallback) ----
__global__ void k_scale_one(const void* __restrict__ f, const float* __restrict__ ns,
                            bf16* __restrict__ P, int nd, const int* __restrict__ mode) {
  int m = *mode;
  int i = blockIdx.x * 256 + threadIdx.x;
  if (i < nd) P[i] = __float2bfloat16(ldf(f, i, m) * ns[i >> 6]);
}

// ---- fused CSR gather + 64x64 matmul (+ optional column stats) ----
// dual: even blocks graph0, odd blocks graph1 (XCD parity split on 8-XCD round-robin).
__global__ void __launch_bounds__(256, 8) k_gmm(
    const bf16* __restrict__ X, const int* __restrict__ rp, const int* __restrict__ sb,
    const void* __restrict__ Wg0, const void* __restrict__ bg0,
    const void* __restrict__ Wg1, const void* __restrict__ bg1,
    const float* __restrict__ pre0, const float* __restrict__ pre1,
    const float* __restrict__ post0, const float* __restrict__ post1,
    bf16* __restrict__ Y, int n, int relu, const int* __restrict__ mode,
    int dual, int gsel, float* __restrict__ stats) {
  int m = *mode;
  int t = threadIdx.x, lane = t & 63, wid = t >> 6;
  int g = dual ? (blockIdx.x & 1) : gsel;
  int ord = dual ? (blockIdx.x >> 1) : blockIdx.x;
  int nblk = dual ? (gridDim.x >> 1) : gridDim.x;
  int rowbase = dual ? g * n : 0;

  const void* W = g ? Wg1 : Wg0;
  const void* bb = g ? bg1 : bg0;
  const float* pre = g ? pre1 : pre0;
  const float* post = g ? post1 : post0;

  unsigned wp[32];
#pragma unroll
  for (int i = 0; i < 32; ++i) {
    unsigned lb = f2bf_bits(ldf(W, (2 * i) * 64 + lane, m));
    unsigned hb = f2bf_bits(ldf(W, (2 * i + 1) * 64 + lane, m));
    wp[i] = lb | (hb << 16);
  }
  float bias = ldf(bb, lane, m);
  float ps = 0.f, pq = 0.f;

  int stride = nblk * 4;
  for (int node = ord * 4 + wid; node < n; node += stride) {
    int b0 = rp[g * n + node], e0 = rp[g * n + node + 1];
    float a0 = 0.f, a1 = 0.f, a2 = 0.f, a3 = 0.f;
    for (int base = b0; base < e0; base += 64) {
      int cnt = e0 - base;
      if (cnt > 64) cnt = 64;
      int eidx = (lane < cnt) ? sb[base + lane] : 0;
      int j = 0;
      for (; j + 8 <= cnt; j += 8) {
        int s0 = __builtin_amdgcn_readlane(eidx, j);
        int s1 = __builtin_amdgcn_readlane(eidx, j + 1);
        int s2 = __builtin_amdgcn_readlane(eidx, j + 2);
        int s3 = __builtin_amdgcn_readlane(eidx, j + 3);
        int s4 = __builtin_amdgcn_readlane(eidx, j + 4);
        int s5 = __builtin_amdgcn_readlane(eidx, j + 5);
        int s6 = __builtin_amdgcn_readlane(eidx, j + 6);
        int s7 = __builtin_amdgcn_readlane(eidx, j + 7);
        float v0 = __bfloat162float(X[(long)(rowbase + s0) * DIM + lane]);
        float v1 = __bfloat162float(X[(long)(rowbase + s1) * DIM + lane]);
        float v2 = __bfloat162float(X[(long)(rowbase + s2) * DIM + lane]);
        float v3 = __bfloat162float(X[(long)(rowbase + s3) * DIM + lane]);
        float v4 = __bfloat162float(X[(long)(rowbase + s4) * DIM + lane]);
        float v5 = __bfloat162float(X[(long)(rowbase + s5) * DIM + lane]);
        float v6 = __bfloat162float(X[(long)(rowbase + s6) * DIM + lane]);
        float v7 = __bfloat162float(X[(long)(rowbase + s7) * DIM + lane]);
        a0 += v0; a1 += v1; a2 += v2; a3 += v3;
        a0 += v4; a1 += v5; a2 += v6; a3 += v7;
      }
      for (; j + 4 <= cnt; j += 4) {
        int s0 = __builtin_amdgcn_readlane(eidx, j);
        int s1 = __builtin_amdgcn_readlane(eidx, j + 1);
        int s2 = __builtin_amdgcn_readlane(eidx, j + 2);
        int s3 = __builtin_amdgcn_readlane(eidx, j + 3);
        a0 += __bfloat162float(X[(long)(rowbase + s0) * DIM + lane]);
        a1 += __bfloat162float(X[(long)(rowbase + s1) * DIM + lane]);
        a2 += __bfloat162float(X[(long)(rowbase + s2) * DIM + lane]);
        a3 += __bfloat162float(X[(long)(rowbase + s3) * DIM + lane]);
      }
      for (; j < cnt; ++j) {
        int s0 = __builtin_amdgcn_readlane(eidx, j);
        a0 += __bfloat162float(X[(long)(rowbase + s0) * DIM + lane]);
      }
    }
    float acc = (a0 + a1) + (a2 + a3);
    acc *= pre[node];
    float r = 0.f;
#pragma unroll
    for (int i = 0; i < 32; ++i) {
      r = fmaf(lane_bcast(acc, 2 * i), __uint_as_float(wp[i] << 16), r);
      r = fmaf(lane_bcast(acc, 2 * i + 1), __uint_as_float(wp[i] & 0xFFFF0000u), r);
    }
    r += bias;
    if (relu) r = fmaxf(r, 0.f);
    if (post) r *= post[node];
    Y[(long)(rowbase + node) * DIM + lane] = __float2bfloat16(r);
    ps += r;
    pq += r * r;
  }

  if (stats) {
    __shared__ float ssum[4][64], ssq[4][64];
    ssum[wid][lane] = ps;
    ssq[wid][lane] = pq;
    __syncthreads();
    if (t < 64) {
      float a = ssum[0][t] + ssum[1][t] + ssum[2][t] + ssum[3][t];
      float b2 = ssq[0][t] + ssq[1][t] + ssq[2][t] + ssq[3][t];
      atomicAdd(&stats[g * 128 + t], a);
      atomicAdd(&stats[g * 128 + 64 + t], b2);
    }
  }
}

// ---- head 64x64 matmul + fused column stats ----
__global__ void __launch_bounds__(256) k_mm64s(const bf16* __restrict__ X,
                                               const void* __restrict__ W,
                                               const void* __restrict__ b,
                                               bf16* __restrict__ Y, int n,
                                               const int* __restrict__ mode,
                                               float* __restrict__ stats) {
  int m = *mode;
  int t = threadIdx.x, lane = t & 63, wid = t >> 6;
  float w[64];
#pragma unroll
  for (int k = 0; k < 64; ++k) w[k] = ldf(W, k * 64 + lane, m);
  float bias = ldf(b, lane, m);
  float ps = 0.f, pq = 0.f;
  int stride = gridDim.x * 4;
  for (int row = blockIdx.x * 4 + wid; row < n; row += stride) {
    float a = __bfloat162float(X[(long)row * 64 + lane]);
    float acc = 0.f;
#pragma unroll
    for (int k = 0; k < 64; ++k) acc = fmaf(lane_bcast(a, k), w[k], acc);
    acc += bias;
    Y[(long)row * 64 + lane] = __float2bfloat16(acc);
    ps += acc;
    pq += acc * acc;
  }
  __shared__ float ssum[4][64], ssq[4][64];
  ssum[wid][lane] = ps;
  ssq[wid][lane] = pq;
  __syncthreads();
  if (t < 64) {
    float a = ssum[0][t] + ssum[1][t] + ssum[2][t] + ssum[3][t];
    float b2 = ssq[0][t] + ssq[1][t] + ssq[2][t] + ssq[3][t];
    atomicAdd(&stats[t], a);
    atomicAdd(&stats[64 + t], b2);
  }
}

// ---- dual standardize: z1, z2 -> out; Dz = 0.5(z1+z2) ----
__global__ void k_z_dual(const bf16* __restrict__ H, const float* __restrict__ stats,
                         void* __restrict__ zout, bf16* __restrict__ Dz, int n,
                         const int* __restrict__ mode) {
  int m = *mode;
  int i = blockIdx.x * 256 + threadIdx.x;
  int nd = n * DIM;
  if (i >= nd) return;
  int c = i & 63;
  float fn = (float)n;
  float mu1 = stats[c] / fn;
  float var1 = fmaxf((stats[64 + c] - mu1 * mu1 * fn) / (fn - 1.0f), 1e-12f);
  float mu2 = stats[128 + c] / fn;
  float var2 = fmaxf((stats[192 + c] - mu2 * mu2 * fn) / (fn - 1.0f), 1e-12f);
  float z1 = (__bfloat162float(H[i]) - mu1) * rsqrtf(var1);
  float z2 = (__bfloat162float(H[nd + i]) - mu2) * rsqrtf(var2);
  stf(zout, i, z1, m);
  stf(zout, (long)nd + i, z2, m);
  Dz[i] = __float2bfloat16(0.5f * (z1 + z2));
}

// ---- sequential standardize (fallback) ----
__global__ void k_z_seq(const bf16* __restrict__ h, const float* __restrict__ stats,
                        void* __restrict__ zout, long zoff, bf16* __restrict__ zacc,
                        int n, int init, const int* __restrict__ mode) {
  int m = *mode;
  int i = blockIdx.x * 256 + threadIdx.x;
  if (i >= n * DIM) return;
  int c = i & 63;
  float fn = (float)n;
  float mu = stats[c] / fn;
  float var = fmaxf((stats[64 + c] - mu * mu * fn) / (fn - 1.0f), 1e-12f);
  float z = (__bfloat162float(h[i]) - mu) * rsqrtf(var);
  stf(zout, zoff + i, z, m);
  float prev = init ? 0.f : __bfloat162float(zacc[i]);
  zacc[i] = __float2bfloat16(prev + 0.5f * z);
}

// ---- BN + relu + 64x40 matmul -> logits ----
__global__ void __launch_bounds__(256) k_head(const bf16* __restrict__ Yv,
                                              const float* __restrict__ s,
                                              const float* __restrict__ sq,
                                              const void* __restrict__ gamma,
                                              const void* __restrict__ beta,
                                              const void* __restrict__ W2,
                                              const void* __restrict__ b2,
                                              void* __restrict__ out, long ooff, int n,
                                              const int* __restrict__ mode) {
  int m = *mode;
  int t = threadIdx.x, lane = t & 63, wid = t >> 6;
  float w[64];
#pragma unroll
  for (int k = 0; k < 64; ++k)
    w[k] = (lane < NCLS_OUT) ? ldf(W2, k * NCLS_OUT + lane, m) : 0.f;
  float bias = (lane < NCLS_OUT) ? ldf(b2, lane, m) : 0.f;
  float fn = (float)n;
  float mu = s[lane] / fn;
  float var = sq[lane] / fn - mu * mu;
  float rstd = rsqrtf(fmaxf(var, 0.f) + 1e-5f);
  float g = ldf(gamma, lane, m);
  float be = ldf(beta, lane, m);
  int stride = gridDim.x * 4;
  for (int row = blockIdx.x * 4 + wid; row < n; row += stride) {
    float yv = __bfloat162float(Yv[(long)row * 64 + lane]);
    float yn = fmaxf((yv - mu) * rstd * g + be, 0.f);
    float acc = bias;
#pragma unroll
    for (int k = 0; k < 64; ++k) acc = fmaf(lane_bcast(yn, k), w[k], acc);
    if (lane < NCLS_OUT) stf(out, ooff + (long)row * NCLS_OUT + lane, acc, m);
  }
}

extern "C" void kernel_launch(void* const* d_in, const int* in_sizes, int n_in,
                              void* d_out, int out_size, void* d_ws, size_t ws_size,
                              hipStream_t stream) {
  const void* feat1 = d_in[0];
  const int* src1 = (const int*)d_in[1];
  const int* dst1 = (const int*)d_in[2];
  const void* feat2 = d_in[3];
  const int* src2 = (const int*)d_in[4];
  const int* dst2 = (const int*)d_in[5];
  const void* W1a = d_in[6];
  const void* b1a = d_in[7];
  const void* W1b = d_in[8];
  const void* b1b = d_in[9];
  const void* W2a = d_in[10];
  const void* b2a = d_in[11];
  const void* W2b = d_in[12];
  const void* b2b = d_in[13];
  const void* Wm1 = d_in[14];
  const void* bm1 = d_in[15];
  const void* gamma = d_in[16];
  const void* beta = d_in[17];
  const void* Wm2 = d_in[18];
  const void* bm2 = d_in[19];

  const int n = in_sizes[0] / DIM;
  const int e1 = in_sizes[1];
  const int e2 = in_sizes[4];
  const int etot = e1 + e2;
  const long nd = (long)n * DIM;

  char* w = (char*)d_ws;
  size_t off = 0;
  auto alloc = [&](size_t bytes) -> void* {
    void* p = w + off;
    off += (bytes + 255) & ~(size_t)255;
    return p;
  };
  // common (~17.5 MB)
  int* mode = (int*)alloc(256);
  int* deg = (int*)alloc((size_t)4 * n * 4);       // [d1in|d2in|d1out|d2out]
  float* stats = (float*)alloc(512 * 4);           // [s1,q1 | s2,q2 | sy,qy]
  float* norms = (float*)alloc((size_t)4 * n * 4); // [nd1|nd2|ns1|ns2]
  int* rp = (int*)alloc((size_t)(2 * n + 8) * 4);
  int* cur = (int*)alloc((size_t)2 * n * 4);
  int* bsum = (int*)alloc(1024 * 4);
  int* sb = (int*)alloc((size_t)etot * 4);
  size_t base_off = off;
  bool dual = (ws_size >= base_off + (size_t)5 * nd * 2 + 4096);

  bf16 *P, *Q, *Dz;
  if (dual) {
    P = (bf16*)alloc((size_t)2 * nd * 2);
    Q = (bf16*)alloc((size_t)2 * nd * 2);
    Dz = (bf16*)alloc((size_t)nd * 2);
  } else {
    P = (bf16*)alloc((size_t)nd * 2);
    Q = (bf16*)alloc((size_t)nd * 2);
    Dz = (bf16*)alloc((size_t)nd * 2);
  }

  const float* nd1 = norms;
  const float* nd2 = norms + n;
  const float* ns1 = norms + 2 * n;
  const float* ns2 = norms + 3 * n;

  int gE = (etot + 255) / 256;
  int gND = (int)((nd + 255) / 256);
  int g2ND = (int)((2 * nd + 255) / 256);
  int g4N = (4 * n + 255) / 256;
  int nb = (2 * n + 1023) / 1024;
  const int gGMM = 2048;

  hipMemsetAsync(deg, 0, (size_t)4 * n * 4, stream);
  hipMemsetAsync(stats, 0, 512 * 4, stream);

  k_detect<<<1, 1024, 0, stream>>>((const unsigned int*)feat1, 8192, mode);
  k_deg_all<<<gE, 256, 0, stream>>>(src1, dst1, src2, dst2, deg, n, e1, etot);
  k_norm<<<g4N, 256, 0, stream>>>(deg, norms, 4 * n);

  // unified CSR over [g1 dsts | g2 dsts]
  k_scan1<<<nb, 256, 0, stream>>>(deg, bsum, 2 * n);
  k_scan2<<<1, 256, 0, stream>>>(bsum, nb);
  k_scan3<<<nb, 256, 0, stream>>>(deg, bsum, rp, 2 * n, etot);
  hipMemcpyAsync(cur, rp, (size_t)2 * n * 4, hipMemcpyDeviceToDevice, stream);
  k_fill_all<<<gE, 256, 0, stream>>>(src1, dst1, src2, dst2, cur, sb, n, e1, etot);

  if (dual) {
    k_scale_all<<<g2ND, 256, 0, stream>>>(feat1, feat2, norms, P, n, mode);
    k_gmm<<<gGMM, 256, 0, stream>>>(P, rp, sb, W1a, b1a, W2a, b2a, nd1, nd2, ns1, ns2,
                                    Q, n, 1, mode, 1, 0, (float*)nullptr);
    k_gmm<<<gGMM, 256, 0, stream>>>(Q, rp, sb, W1b, b1b, W2b, b2b, nd1, nd2,
                                    (const float*)nullptr, (const float*)nullptr,
                                    P, n, 0, mode, 1, 0, stats);
    k_z_dual<<<gND, 256, 0, stream>>>(P, stats, d_out, Dz, n, mode);
  } else {
    // graph 1
    k_scale_one<<<gND, 256, 0, stream>>>(feat1, ns1, P, (int)nd, mode);
    k_gmm<<<gGMM, 256, 0, stream>>>(P, rp, sb, W1a, b1a, W1a, b1a, nd1, nd1, ns1, ns1,
                                    Q, n, 1, mode, 0, 0, (float*)nullptr);
    k_gmm<<<gGMM, 256, 0, stream>>>(Q, rp, sb, W1b, b1b, W1b, b1b, nd1, nd1,
                                    (const float*)nullptr, (const float*)nullptr,
                                    P, n, 0, mode, 0, 0, stats);
    k_z_seq<<<gND, 256, 0, stream>>>(P, stats, d_out, 0L, Dz, n, 1, mode);
    // graph 2
    k_scale_one<<<gND, 256, 0, stream>>>(feat2, ns2, P, (int)nd, mode);
    k_gmm<<<gGMM, 256, 0, stream>>>(P, rp, sb, W2a, b2a, W2a, b2a, nd2, nd2, ns2, ns2,
                                    Q, n, 1, mode, 0, 1, (float*)nullptr);
    k_gmm<<<gGMM, 256, 0, stream>>>(Q, rp, sb, W2b, b2b, W2b, b2b, nd2, nd2,
                                    (const float*)nullptr, (const float*)nullptr,
                                    P, n, 0, mode, 0, 1, stats + 128);
    k_z_seq<<<gND, 256, 0, stream>>>(P, stats + 128, d_out, nd, Dz, n, 0, mode);
  }

  // head: y = Dz@Wm1+bm1 (stats fused) ; BN ; relu ; @Wm2+bm2
  k_mm64s<<<512, 256, 0, stream>>>(Dz, Wm1, bm1, Q, n, mode, stats + 256);
  k_head<<<512, 256, 0, stream>>>(Q, stats + 256, stats + 320, gamma, beta, Wm2, bm2,
                                  d_out, 2 * nd, n, mode);
}

// Round 6
// 1261.733 us; speedup vs baseline: 1.2762x; 1.2762x over previous
//
#include <hip/hip_runtime.h>
#include <hip/hip_bf16.h>

#define DIM 64
#define NCLS_OUT 40

typedef __hip_bfloat16 bf16;

__device__ __forceinline__ float lane_bcast(float v, int l) {
  return __int_as_float(__builtin_amdgcn_readlane(__float_as_int(v), l));
}
__device__ __forceinline__ unsigned short f2bf_bits(float f) {
  bf16 h = __float2bfloat16(f);
  return *reinterpret_cast<unsigned short*>(&h);
}

// mode: 1 = float inputs/outputs stored as f32, 0 = stored as bf16
__device__ __forceinline__ float ldf(const void* p, long i, int m) {
  return m ? ((const float*)p)[i] : __bfloat162float(((const bf16*)p)[i]);
}
__device__ __forceinline__ void stf(void* p, long i, float v, int m) {
  if (m) ((float*)p)[i] = v;
  else ((bf16*)p)[i] = __float2bfloat16(v);
}

// ---- dtype detector ----
__global__ void k_detect(const unsigned int* __restrict__ wds, int nw, int* __restrict__ mode) {
  __shared__ int cnt_s;
  if (threadIdx.x == 0) cnt_s = 0;
  __syncthreads();
  int c = 0;
  for (int i = threadIdx.x; i < nw; i += 1024) {
    unsigned h = wds[i] & 0xFFFFu;
    unsigned e = (h >> 7) & 0xFFu;
    if (e == 0xFFu || (e != 0u && e < 0x60u)) c++;
  }
  atomicAdd(&cnt_s, c);
  __syncthreads();
  if (threadIdx.x == 0) *mode = (cnt_s > nw / 16) ? 1 : 0;
}

// ---- degree count, both graphs, one dispatch ----
// deg layout: [d1in | d2in | d1out | d2out]
__global__ void k_deg_all(const int* __restrict__ src1, const int* __restrict__ dst1,
                          const int* __restrict__ src2, const int* __restrict__ dst2,
                          int* __restrict__ deg, int n, int e1, int etot) {
  int i = blockIdx.x * 256 + threadIdx.x;
  if (i >= etot) return;
  if (i < e1) {
    atomicAdd(&deg[dst1[i]], 1);
    atomicAdd(&deg[2 * n + src1[i]], 1);
  } else {
    int j = i - e1;
    atomicAdd(&deg[n + dst2[j]], 1);
    atomicAdd(&deg[3 * n + src2[j]], 1);
  }
}

// ---- norms = rsqrt(max(deg,1)); layout mirrors deg: [nd1|nd2|ns1|ns2] ----
__global__ void k_norm(const int* __restrict__ deg, float* __restrict__ nrm, int n4) {
  int i = blockIdx.x * 256 + threadIdx.x;
  if (i < n4) {
    int d = deg[i];
    if (d < 1) d = 1;
    nrm[i] = rsqrtf((float)d);
  }
}

// ---- scan pass 1 ----
__global__ void k_scan1(const int* __restrict__ x, int* __restrict__ bsum, int n) {
  __shared__ int sm[256];
  int t = threadIdx.x;
  int base = blockIdx.x * 1024 + t * 4;
  int s = 0;
#pragma unroll
  for (int k = 0; k < 4; ++k) {
    int i = base + k;
    if (i < n) s += x[i];
  }
  sm[t] = s;
  __syncthreads();
  for (int o = 128; o > 0; o >>= 1) {
    if (t < o) sm[t] += sm[t + o];
    __syncthreads();
  }
  if (t == 0) bsum[blockIdx.x] = sm[0];
}

// ---- scan pass 2 ----
__global__ void k_scan2(int* __restrict__ bsum, int nb) {
  __shared__ int sm[256];
  __shared__ int carry_s;
  int t = threadIdx.x;
  if (t == 0) carry_s = 0;
  __syncthreads();
  for (int base = 0; base < nb; base += 256) {
    int i = base + t;
    int v = (i < nb) ? bsum[i] : 0;
    sm[t] = v;
    __syncthreads();
    for (int o = 1; o < 256; o <<= 1) {
      int a = (t >= o) ? sm[t - o] : 0;
      __syncthreads();
      sm[t] += a;
      __syncthreads();
    }
    int incl = sm[t];
    int tot = sm[255];
    int c = carry_s;
    __syncthreads();
    if (i < nb) bsum[i] = c + incl - v;
    if (t == 0) carry_s = c + tot;
    __syncthreads();
  }
}

// ---- scan pass 3 ----
__global__ void k_scan3(const int* __restrict__ x, const int* __restrict__ bsum,
                        int* __restrict__ rp, int n, int e) {
  __shared__ int sm[256];
  int t = threadIdx.x;
  int base = blockIdx.x * 1024;
  int v[4];
  int s = 0;
#pragma unroll
  for (int k = 0; k < 4; ++k) {
    int i = base + t * 4 + k;
    v[k] = (i < n) ? x[i] : 0;
    s += v[k];
  }
  sm[t] = s;
  __syncthreads();
  for (int o = 1; o < 256; o <<= 1) {
    int a = (t >= o) ? sm[t - o] : 0;
    __syncthreads();
    sm[t] += a;
    __syncthreads();
  }
  int excl = bsum[blockIdx.x] + sm[t] - s;
#pragma unroll
  for (int k = 0; k < 4; ++k) {
    int i = base + t * 4 + k;
    if (i < n) {
      rp[i] = excl;
      excl += v[k];
    }
  }
  if (blockIdx.x == 0 && t == 0) rp[n] = e;
}

// ---- bucket fill, both graphs, unified sb ----
__global__ void k_fill_all(const int* __restrict__ src1, const int* __restrict__ dst1,
                           const int* __restrict__ src2, const int* __restrict__ dst2,
                           int* __restrict__ cur, int* __restrict__ sb,
                           int n, int e1, int etot) {
  int i = blockIdx.x * 256 + threadIdx.x;
  if (i >= etot) return;
  int s, ridx;
  if (i < e1) { s = src1[i]; ridx = dst1[i]; }
  else { int j = i - e1; s = src2[j]; ridx = n + dst2[j]; }
  int pos = atomicAdd(&cur[ridx], 1);
  if ((unsigned)pos < (unsigned)etot) sb[pos] = s;
}

// ---- P = feat * ns, both graphs -> P[2n][64] ----
__global__ void k_scale_all(const void* __restrict__ f1, const void* __restrict__ f2,
                            const float* __restrict__ norms, bf16* __restrict__ P,
                            int n, const int* __restrict__ mode) {
  int m = *mode;
  int i = blockIdx.x * 256 + threadIdx.x;
  int nd = n * DIM;
  if (i >= 2 * nd) return;
  int g = i >= nd;
  int li = g ? i - nd : i;
  float ns = norms[2 * n + g * n + (li >> 6)];
  P[i] = __float2bfloat16(ldf(g ? f2 : f1, li, m) * ns);
}

// ---- P = feat * ns, one graph (fallback) ----
__global__ void k_scale_one(const void* __restrict__ f, const float* __restrict__ ns,
                            bf16* __restrict__ P, int nd, const int* __restrict__ mode) {
  int m = *mode;
  int i = blockIdx.x * 256 + threadIdx.x;
  if (i < nd) P[i] = __float2bfloat16(ldf(f, i, m) * ns[i >> 6]);
}

// ---- fused CSR gather + 64x64 matmul (+ optional column stats) ----
// dual: even blocks graph0, odd blocks graph1 (XCD parity on 8-XCD round-robin).
// NOTE: no min-waves clause — a VGPR cap below ~56 spills wp[] to scratch
// (round-5: FETCH_SIZE 84MB -> 1.01GB, 420us). Keep the allocator free.
__global__ void __launch_bounds__(256) k_gmm(
    const bf16* __restrict__ X, const int* __restrict__ rp, const int* __restrict__ sb,
    const void* __restrict__ Wg0, const void* __restrict__ bg0,
    const void* __restrict__ Wg1, const void* __restrict__ bg1,
    const float* __restrict__ pre0, const float* __restrict__ pre1,
    const float* __restrict__ post0, const float* __restrict__ post1,
    bf16* __restrict__ Y, int n, int relu, const int* __restrict__ mode,
    int dual, int gsel, float* __restrict__ stats) {
  int m = *mode;
  int t = threadIdx.x, lane = t & 63, wid = t >> 6;
  int g = dual ? (blockIdx.x & 1) : gsel;
  int ord = dual ? (blockIdx.x >> 1) : blockIdx.x;
  int nblk = dual ? (gridDim.x >> 1) : gridDim.x;
  int rowbase = dual ? g * n : 0;

  const void* W = g ? Wg1 : Wg0;
  const void* bb = g ? bg1 : bg0;
  const float* pre = g ? pre1 : pre0;
  const float* post = g ? post1 : post0;

  unsigned wp[32];
#pragma unroll
  for (int i = 0; i < 32; ++i) {
    unsigned lb = f2bf_bits(ldf(W, (2 * i) * 64 + lane, m));
    unsigned hb = f2bf_bits(ldf(W, (2 * i + 1) * 64 + lane, m));
    wp[i] = lb | (hb << 16);
  }
  float bias = ldf(bb, lane, m);
  float ps = 0.f, pq = 0.f;

  int stride = nblk * 4;
  for (int node = ord * 4 + wid; node < n; node += stride) {
    int b0 = rp[g * n + node], e0 = rp[g * n + node + 1];
    float a0 = 0.f, a1 = 0.f, a2 = 0.f, a3 = 0.f;
    for (int base = b0; base < e0; base += 64) {
      int cnt = e0 - base;
      if (cnt > 64) cnt = 64;
      int eidx = (lane < cnt) ? sb[base + lane] : 0;
      int j = 0;
      for (; j + 8 <= cnt; j += 8) {
        int s0 = __builtin_amdgcn_readlane(eidx, j);
        int s1 = __builtin_amdgcn_readlane(eidx, j + 1);
        int s2 = __builtin_amdgcn_readlane(eidx, j + 2);
        int s3 = __builtin_amdgcn_readlane(eidx, j + 3);
        int s4 = __builtin_amdgcn_readlane(eidx, j + 4);
        int s5 = __builtin_amdgcn_readlane(eidx, j + 5);
        int s6 = __builtin_amdgcn_readlane(eidx, j + 6);
        int s7 = __builtin_amdgcn_readlane(eidx, j + 7);
        float v0 = __bfloat162float(X[(long)(rowbase + s0) * DIM + lane]);
        float v1 = __bfloat162float(X[(long)(rowbase + s1) * DIM + lane]);
        float v2 = __bfloat162float(X[(long)(rowbase + s2) * DIM + lane]);
        float v3 = __bfloat162float(X[(long)(rowbase + s3) * DIM + lane]);
        float v4 = __bfloat162float(X[(long)(rowbase + s4) * DIM + lane]);
        float v5 = __bfloat162float(X[(long)(rowbase + s5) * DIM + lane]);
        float v6 = __bfloat162float(X[(long)(rowbase + s6) * DIM + lane]);
        float v7 = __bfloat162float(X[(long)(rowbase + s7) * DIM + lane]);
        a0 += v0; a1 += v1; a2 += v2; a3 += v3;
        a0 += v4; a1 += v5; a2 += v6; a3 += v7;
      }
      for (; j + 4 <= cnt; j += 4) {
        int s0 = __builtin_amdgcn_readlane(eidx, j);
        int s1 = __builtin_amdgcn_readlane(eidx, j + 1);
        int s2 = __builtin_amdgcn_readlane(eidx, j + 2);
        int s3 = __builtin_amdgcn_readlane(eidx, j + 3);
        a0 += __bfloat162float(X[(long)(rowbase + s0) * DIM + lane]);
        a1 += __bfloat162float(X[(long)(rowbase + s1) * DIM + lane]);
        a2 += __bfloat162float(X[(long)(rowbase + s2) * DIM + lane]);
        a3 += __bfloat162float(X[(long)(rowbase + s3) * DIM + lane]);
      }
      for (; j < cnt; ++j) {
        int s0 = __builtin_amdgcn_readlane(eidx, j);
        a0 += __bfloat162float(X[(long)(rowbase + s0) * DIM + lane]);
      }
    }
    float acc = (a0 + a1) + (a2 + a3);
    acc *= pre[node];
    float r = 0.f;
#pragma unroll
    for (int i = 0; i < 32; ++i) {
      r = fmaf(lane_bcast(acc, 2 * i), __uint_as_float(wp[i] << 16), r);
      r = fmaf(lane_bcast(acc, 2 * i + 1), __uint_as_float(wp[i] & 0xFFFF0000u), r);
    }
    r += bias;
    if (relu) r = fmaxf(r, 0.f);
    if (post) r *= post[node];
    Y[(long)(rowbase + node) * DIM + lane] = __float2bfloat16(r);
    ps += r;
    pq += r * r;
  }

  if (stats) {
    __shared__ float ssum[4][64], ssq[4][64];
    ssum[wid][lane] = ps;
    ssq[wid][lane] = pq;
    __syncthreads();
    if (t < 64) {
      float a = ssum[0][t] + ssum[1][t] + ssum[2][t] + ssum[3][t];
      float b2 = ssq[0][t] + ssq[1][t] + ssq[2][t] + ssq[3][t];
      atomicAdd(&stats[g * 128 + t], a);
      atomicAdd(&stats[g * 128 + 64 + t], b2);
    }
  }
}

// ---- head 64x64 matmul + fused column stats ----
__global__ void __launch_bounds__(256) k_mm64s(const bf16* __restrict__ X,
                                               const void* __restrict__ W,
                                               const void* __restrict__ b,
                                               bf16* __restrict__ Y, int n,
                                               const int* __restrict__ mode,
                                               float* __restrict__ stats) {
  int m = *mode;
  int t = threadIdx.x, lane = t & 63, wid = t >> 6;
  float w[64];
#pragma unroll
  for (int k = 0; k < 64; ++k) w[k] = ldf(W, k * 64 + lane, m);
  float bias = ldf(b, lane, m);
  float ps = 0.f, pq = 0.f;
  int stride = gridDim.x * 4;
  for (int row = blockIdx.x * 4 + wid; row < n; row += stride) {
    float a = __bfloat162float(X[(long)row * 64 + lane]);
    float acc = 0.f;
#pragma unroll
    for (int k = 0; k < 64; ++k) acc = fmaf(lane_bcast(a, k), w[k], acc);
    acc += bias;
    Y[(long)row * 64 + lane] = __float2bfloat16(acc);
    ps += acc;
    pq += acc * acc;
  }
  __shared__ float ssum[4][64], ssq[4][64];
  ssum[wid][lane] = ps;
  ssq[wid][lane] = pq;
  __syncthreads();
  if (t < 64) {
    float a = ssum[0][t] + ssum[1][t] + ssum[2][t] + ssum[3][t];
    float b2 = ssq[0][t] + ssq[1][t] + ssq[2][t] + ssq[3][t];
    atomicAdd(&stats[t], a);
    atomicAdd(&stats[64 + t], b2);
  }
}

// ---- dual standardize: z1, z2 -> out; Dz = 0.5(z1+z2) ----
__global__ void k_z_dual(const bf16* __restrict__ H, const float* __restrict__ stats,
                         void* __restrict__ zout, bf16* __restrict__ Dz, int n,
                         const int* __restrict__ mode) {
  int m = *mode;
  int i = blockIdx.x * 256 + threadIdx.x;
  int nd = n * DIM;
  if (i >= nd) return;
  int c = i & 63;
  float fn = (float)n;
  float mu1 = stats[c] / fn;
  float var1 = fmaxf((stats[64 + c] - mu1 * mu1 * fn) / (fn - 1.0f), 1e-12f);
  float mu2 = stats[128 + c] / fn;
  float var2 = fmaxf((stats[192 + c] - mu2 * mu2 * fn) / (fn - 1.0f), 1e-12f);
  float z1 = (__bfloat162float(H[i]) - mu1) * rsqrtf(var1);
  float z2 = (__bfloat162float(H[nd + i]) - mu2) * rsqrtf(var2);
  stf(zout, i, z1, m);
  stf(zout, (long)nd + i, z2, m);
  Dz[i] = __float2bfloat16(0.5f * (z1 + z2));
}

// ---- sequential standardize (fallback) ----
__global__ void k_z_seq(const bf16* __restrict__ h, const float* __restrict__ stats,
                        void* __restrict__ zout, long zoff, bf16* __restrict__ zacc,
                        int n, int init, const int* __restrict__ mode) {
  int m = *mode;
  int i = blockIdx.x * 256 + threadIdx.x;
  if (i >= n * DIM) return;
  int c = i & 63;
  float fn = (float)n;
  float mu = stats[c] / fn;
  float var = fmaxf((stats[64 + c] - mu * mu * fn) / (fn - 1.0f), 1e-12f);
  float z = (__bfloat162float(h[i]) - mu) * rsqrtf(var);
  stf(zout, zoff + i, z, m);
  float prev = init ? 0.f : __bfloat162float(zacc[i]);
  zacc[i] = __float2bfloat16(prev + 0.5f * z);
}

// ---- BN + relu + 64x40 matmul -> logits ----
__global__ void __launch_bounds__(256) k_head(const bf16* __restrict__ Yv,
                                              const float* __restrict__ s,
                                              const float* __restrict__ sq,
                                              const void* __restrict__ gamma,
                                              const void* __restrict__ beta,
                                              const void* __restrict__ W2,
                                              const void* __restrict__ b2,
                                              void* __restrict__ out, long ooff, int n,
                                              const int* __restrict__ mode) {
  int m = *mode;
  int t = threadIdx.x, lane = t & 63, wid = t >> 6;
  float w[64];
#pragma unroll
  for (int k = 0; k < 64; ++k)
    w[k] = (lane < NCLS_OUT) ? ldf(W2, k * NCLS_OUT + lane, m) : 0.f;
  float bias = (lane < NCLS_OUT) ? ldf(b2, lane, m) : 0.f;
  float fn = (float)n;
  float mu = s[lane] / fn;
  float var = sq[lane] / fn - mu * mu;
  float rstd = rsqrtf(fmaxf(var, 0.f) + 1e-5f);
  float g = ldf(gamma, lane, m);
  float be = ldf(beta, lane, m);
  int stride = gridDim.x * 4;
  for (int row = blockIdx.x * 4 + wid; row < n; row += stride) {
    float yv = __bfloat162float(Yv[(long)row * 64 + lane]);
    float yn = fmaxf((yv - mu) * rstd * g + be, 0.f);
    float acc = bias;
#pragma unroll
    for (int k = 0; k < 64; ++k) acc = fmaf(lane_bcast(yn, k), w[k], acc);
    if (lane < NCLS_OUT) stf(out, ooff + (long)row * NCLS_OUT + lane, acc, m);
  }
}

extern "C" void kernel_launch(void* const* d_in, const int* in_sizes, int n_in,
                              void* d_out, int out_size, void* d_ws, size_t ws_size,
                              hipStream_t stream) {
  const void* feat1 = d_in[0];
  const int* src1 = (const int*)d_in[1];
  const int* dst1 = (const int*)d_in[2];
  const void* feat2 = d_in[3];
  const int* src2 = (const int*)d_in[4];
  const int* dst2 = (const int*)d_in[5];
  const void* W1a = d_in[6];
  const void* b1a = d_in[7];
  const void* W1b = d_in[8];
  const void* b1b = d_in[9];
  const void* W2a = d_in[10];
  const void* b2a = d_in[11];
  const void* W2b = d_in[12];
  const void* b2b = d_in[13];
  const void* Wm1 = d_in[14];
  const void* bm1 = d_in[15];
  const void* gamma = d_in[16];
  const void* beta = d_in[17];
  const void* Wm2 = d_in[18];
  const void* bm2 = d_in[19];

  const int n = in_sizes[0] / DIM;
  const int e1 = in_sizes[1];
  const int e2 = in_sizes[4];
  const int etot = e1 + e2;
  const long nd = (long)n * DIM;

  char* w = (char*)d_ws;
  size_t off = 0;
  auto alloc = [&](size_t bytes) -> void* {
    void* p = w + off;
    off += (bytes + 255) & ~(size_t)255;
    return p;
  };
  int* mode = (int*)alloc(256);
  int* deg = (int*)alloc((size_t)4 * n * 4);
  float* stats = (float*)alloc(512 * 4);
  float* norms = (float*)alloc((size_t)4 * n * 4);
  int* rp = (int*)alloc((size_t)(2 * n + 8) * 4);
  int* cur = (int*)alloc((size_t)2 * n * 4);
  int* bsum = (int*)alloc(1024 * 4);
  int* sb = (int*)alloc((size_t)etot * 4);
  size_t base_off = off;
  bool dual = (ws_size >= base_off + (size_t)5 * nd * 2 + 4096);

  bf16 *P, *Q, *Dz;
  if (dual) {
    P = (bf16*)alloc((size_t)2 * nd * 2);
    Q = (bf16*)alloc((size_t)2 * nd * 2);
    Dz = (bf16*)alloc((size_t)nd * 2);
  } else {
    P = (bf16*)alloc((size_t)nd * 2);
    Q = (bf16*)alloc((size_t)nd * 2);
    Dz = (bf16*)alloc((size_t)nd * 2);
  }

  const float* nd1 = norms;
  const float* nd2 = norms + n;
  const float* ns1 = norms + 2 * n;
  const float* ns2 = norms + 3 * n;

  int gE = (etot + 255) / 256;
  int gND = (int)((nd + 255) / 256);
  int g2ND = (int)((2 * nd + 255) / 256);
  int g4N = (4 * n + 255) / 256;
  int nb = (2 * n + 1023) / 1024;
  const int gGMM = 4096;

  hipMemsetAsync(deg, 0, (size_t)4 * n * 4, stream);
  hipMemsetAsync(stats, 0, 512 * 4, stream);

  k_detect<<<1, 1024, 0, stream>>>((const unsigned int*)feat1, 8192, mode);
  k_deg_all<<<gE, 256, 0, stream>>>(src1, dst1, src2, dst2, deg, n, e1, etot);
  k_norm<<<g4N, 256, 0, stream>>>(deg, norms, 4 * n);

  // unified CSR over [g1 dsts | g2 dsts]
  k_scan1<<<nb, 256, 0, stream>>>(deg, bsum, 2 * n);
  k_scan2<<<1, 256, 0, stream>>>(bsum, nb);
  k_scan3<<<nb, 256, 0, stream>>>(deg, bsum, rp, 2 * n, etot);
  hipMemcpyAsync(cur, rp, (size_t)2 * n * 4, hipMemcpyDeviceToDevice, stream);
  k_fill_all<<<gE, 256, 0, stream>>>(src1, dst1, src2, dst2, cur, sb, n, e1, etot);

  if (dual) {
    k_scale_all<<<g2ND, 256, 0, stream>>>(feat1, feat2, norms, P, n, mode);
    k_gmm<<<gGMM, 256, 0, stream>>>(P, rp, sb, W1a, b1a, W2a, b2a, nd1, nd2, ns1, ns2,
                                    Q, n, 1, mode, 1, 0, (float*)nullptr);
    k_gmm<<<gGMM, 256, 0, stream>>>(Q, rp, sb, W1b, b1b, W2b, b2b, nd1, nd2,
                                    (const float*)nullptr, (const float*)nullptr,
                                    P, n, 0, mode, 1, 0, stats);
    k_z_dual<<<gND, 256, 0, stream>>>(P, stats, d_out, Dz, n, mode);
  } else {
    // graph 1
    k_scale_one<<<gND, 256, 0, stream>>>(feat1, ns1, P, (int)nd, mode);
    k_gmm<<<gGMM, 256, 0, stream>>>(P, rp, sb, W1a, b1a, W1a, b1a, nd1, nd1, ns1, ns1,
                                    Q, n, 1, mode, 0, 0, (float*)nullptr);
    k_gmm<<<gGMM, 256, 0, stream>>>(Q, rp, sb, W1b, b1b, W1b, b1b, nd1, nd1,
                                    (const float*)nullptr, (const float*)nullptr,
                                    P, n, 0, mode, 0, 0, stats);
    k_z_seq<<<gND, 256, 0, stream>>>(P, stats, d_out, 0L, Dz, n, 1, mode);
    // graph 2
    k_scale_one<<<gND, 256, 0, stream>>>(feat2, ns2, P, (int)nd, mode);
    k_gmm<<<gGMM, 256, 0, stream>>>(P, rp, sb, W2a, b2a, W2a, b2a, nd2, nd2, ns2, ns2,
                                    Q, n, 1, mode, 0, 1, (float*)nullptr);
    k_gmm<<<gGMM, 256, 0, stream>>>(Q, rp, sb, W2b, b2b, W2b, b2b, nd2, nd2,
                                    (const float*)nullptr, (const float*)nullptr,
                                    P, n, 0, mode, 0, 1, stats + 128);
    k_z_seq<<<gND, 256, 0, stream>>>(P, stats + 128, d_out, nd, Dz, n, 0, mode);
  }

  // head: y = Dz@Wm1+bm1 (stats fused) ; BN ; relu ; @Wm2+bm2
  k_mm64s<<<512, 256, 0, stream>>>(Dz, Wm1, bm1, Q, n, mode, stats + 256);
  k_head<<<512, 256, 0, stream>>>(Q, stats + 256, stats + 320, gamma, beta, Wm2, bm2,
                                  d_out, 2 * nd, n, mode);
}